// Round 4
// baseline (251527.759 us; speedup 1.0000x reference)
//
#include <hip/hip_runtime.h>
#include <stdint.h>
#include <math.h>

// Problem dims
#define Bn 256
#define Sn 512
#define En 256
#define Hn 256
#define Gn 1024            // 4*H
#define NSTEP 511          // S-1 decoder steps
#define MASK_VAL -100000.0

// Verified rounds 1-3,7-11: partitionable threefry + f64 compute -> absmax=0.
#define PARTITIONABLE 1

// ---------------------------------------------------------------- threefry
__device__ __forceinline__ uint32_t rotl32(uint32_t v, int d) {
  return (v << d) | (v >> (32 - d));
}

__device__ __forceinline__ void threefry2x32(uint32_t k0, uint32_t k1,
                                             uint32_t x0, uint32_t x1,
                                             uint32_t& o0, uint32_t& o1) {
  const uint32_t ks2 = k0 ^ k1 ^ 0x1BD11BDAu;
  x0 += k0; x1 += k1;
  x0 += x1; x1 = rotl32(x1, 13); x1 ^= x0;
  x0 += x1; x1 = rotl32(x1, 15); x1 ^= x0;
  x0 += x1; x1 = rotl32(x1, 26); x1 ^= x0;
  x0 += x1; x1 = rotl32(x1,  6); x1 ^= x0;
  x0 += k1; x1 += ks2 + 1u;
  x0 += x1; x1 = rotl32(x1, 17); x1 ^= x0;
  x0 += x1; x1 = rotl32(x1, 29); x1 ^= x0;
  x0 += x1; x1 = rotl32(x1, 16); x1 ^= x0;
  x0 += x1; x1 = rotl32(x1, 24); x1 ^= x0;
  x0 += ks2; x1 += k0 + 2u;
  x0 += x1; x1 = rotl32(x1, 13); x1 ^= x0;
  x0 += x1; x1 = rotl32(x1, 15); x1 ^= x0;
  x0 += x1; x1 = rotl32(x1, 26); x1 ^= x0;
  x0 += x1; x1 = rotl32(x1,  6); x1 ^= x0;
  x0 += k0; x1 += k1 + 3u;
  x0 += x1; x1 = rotl32(x1, 17); x1 ^= x0;
  x0 += x1; x1 = rotl32(x1, 29); x1 ^= x0;
  x0 += x1; x1 = rotl32(x1, 16); x1 ^= x0;
  x0 += x1; x1 = rotl32(x1, 24); x1 ^= x0;
  x0 += k1; x1 += ks2 + 4u;
  x0 += x1; x1 = rotl32(x1, 13); x1 ^= x0;
  x0 += x1; x1 = rotl32(x1, 15); x1 ^= x0;
  x0 += x1; x1 = rotl32(x1, 26); x1 ^= x0;
  x0 += x1; x1 = rotl32(x1,  6); x1 ^= x0;
  x0 += ks2; x1 += k0 + 5u;
  o0 = x0; o1 = x1;
}

__device__ __forceinline__ uint32_t random_word(uint32_t k0, uint32_t k1, uint32_t n) {
#if PARTITIONABLE
  uint32_t o0, o1;
  threefry2x32(k0, k1, 0u, n, o0, o1);
  return o0 ^ o1;
#else
  const uint32_t half = (Bn * Sn) / 2;
  uint32_t lane = (n < half) ? n : (n - half);
  uint32_t o0, o1;
  threefry2x32(k0, k1, lane, lane + half, o0, o1);
  return (n < half) ? o0 : o1;
#endif
}

__device__ __forceinline__ double sigmoid64(double x) {
  return 1.0 / (1.0 + exp(-x));
}

// ---------------------------------------------------------------- prep
__global__ __launch_bounds__(256) void k_wihe(const float* __restrict__ wemb,
                                              const float* __restrict__ wih,
                                              const float* __restrict__ bih,
                                              const float* __restrict__ bhh,
                                              double* __restrict__ wihe,
                                              double* __restrict__ bias) {
  int j = blockIdx.x * blockDim.x + threadIdx.x;
  if (j >= Gn) return;
  double a0 = 0.0, a1 = 0.0;
  for (int e = 0; e < En; ++e) {
    double w = (double)wih[j * En + e];
    a0 += (double)wemb[e] * w;
    a1 += (double)wemb[En + e] * w;
  }
  wihe[j] = a0;
  wihe[Gn + j] = a1;
  bias[j] = (double)bih[j] + (double)bhh[j];
}

__global__ __launch_bounds__(256) void k_keys(uint32_t* __restrict__ keys) {
  int j = blockIdx.x * blockDim.x + threadIdx.x;
  if (j >= NSTEP) return;
#if PARTITIONABLE
  uint32_t o0, o1;
  threefry2x32(0u, 1u, 0u, (uint32_t)j, o0, o1);
  keys[2 * j] = o0; keys[2 * j + 1] = o1;
#else
  uint32_t w[2];
  #pragma unroll
  for (int q = 0; q < 2; ++q) {
    uint32_t m = (uint32_t)(2 * j + q);
    uint32_t lane = (m < NSTEP) ? m : (m - NSTEP);
    uint32_t o0, o1;
    threefry2x32(0u, 1u, lane, lane + NSTEP, o0, o1);
    w[q] = (m < NSTEP) ? o0 : o1;
  }
  keys[2 * j] = w[0]; keys[2 * j + 1] = w[1];
#endif
}

// Packed-coalesced weight layouts.
// whh2[((k4*1024 + j)*4 + r)] = Whh[j][k4*4 + r]  -> wave loads 64 lanes x
// float4 = 1KB contiguous per instr; per-thread element order is still
// k-ascending (bit-identical accumulation).
__global__ __launch_bounds__(256) void k_pack_whh(const float* __restrict__ src,
                                                  float* __restrict__ dst) {
  int o = blockIdx.x * 256 + threadIdx.x;          // 64*1024*4 = 262144
  int r = o & 3, j = (o >> 2) & 1023, k4 = o >> 12;
  dst[o] = src[j * Hn + k4 * 4 + r];
}

// wp[(((p*16 + i4)*256 + tcol)*4 + r)] = W[tcol][p*64 + i4*4 + r]
__global__ __launch_bounds__(256) void k_pack_w256(const float* __restrict__ src,
                                                   float* __restrict__ dst) {
  int o = blockIdx.x * 256 + threadIdx.x;          // 4*16*256*4 = 65536
  int r = o & 3, tcol = (o >> 2) & 255, i4 = (o >> 10) & 15, p = o >> 14;
  dst[o] = src[tcol * Hn + p * 64 + i4 * 4 + r];
}

__global__ __launch_bounds__(256) void k_init(float* __restrict__ out) {
  int idx = blockIdx.x * blockDim.x + threadIdx.x;
  if (idx < Bn) out[Bn * NSTEP + idx * Sn] = 0.0f;   // indices[:,0] = START
}

// ---------------------------------------------------------------- main
// Block b owns batch row b end-to-end. Base = r14 (29.5 ms, absmax 0).
// r15: latency-stall attack (r14 post-mortem: VALUBusy 58->46 with flat
// time => critical path is memory LATENCY, not VALU issue). All changes
// are pure scheduling; every FP value and accumulation order bit-identical.
//  1. Logits 3-deep static pipeline: group0 issued after S2 (hides under
//     qproj), group1 after S3, group2 after S4; consume/refill chain is
//     macro-expanded with NAMED buffers sA/sB/sC (all static indices --
//     no r13 scratch trap). 2-3 groups (64-96B/thread) always in flight.
//  2. Gates/qproj/refproj: group-level ping-pong prefetch (bA/bB float4[4]
//     named buffers, consume g while g+1 in flight, refill g+2 after) --
//     bounded registers by construction, cross-group latency hidden.
struct AttnS {
  double qpart[4][256];   // 8 KB
  double p2[2][512];      // 8 KB
  double sg[2][512];      // 8 KB  gumbel, double-buffered by t&1
  float2 qv2[256];        // 2 KB  {qf, v} fused
};

// ---- gate matvec: consume group g (k4 = 4g..4g+3), acc order identical
#define GGRP(BUF, g)                                                    \
  { _Pragma("unroll")                                                   \
    for (int q = 0; q < 4; ++q) {                                       \
      double2 h0 = *(const double2*)&sh_h[16 * (g) + 4 * q];            \
      double2 h1 = *(const double2*)&sh_h[16 * (g) + 4 * q + 2];        \
      acc += h0.x * (double)BUF[q].x;                                   \
      acc += h0.y * (double)BUF[q].y;                                   \
      acc += h1.x * (double)BUF[q].z;                                   \
      acc += h1.y * (double)BUF[q].w;                                   \
    } }
#define GLD(BUF, g, WP)                                                 \
  { _Pragma("unroll")                                                   \
    for (int q = 0; q < 4; ++q) BUF[q] = WP[(size_t)(4 * (g) + q) << 10]; }
#define GSTEP(BUF, g, WP)  GGRP(BUF, g) if ((g) + 2 < 16) GLD(BUF, (g) + 2, WP)

// ---- 256x256 proj: consume group g (i4 = 4g..4g+3)
#define QGRP(BUF, g, ACC)                                               \
  { _Pragma("unroll")                                                   \
    for (int q = 0; q < 4; ++q) {                                       \
      int kb = part * 64 + (4 * (g) + q) * 4;                           \
      double2 h0 = *(const double2*)&sh_h[kb];                          \
      double2 h1 = *(const double2*)&sh_h[kb + 2];                      \
      ACC += h0.x * (double)BUF[q].x;                                   \
      ACC += h0.y * (double)BUF[q].y;                                   \
      ACC += h1.x * (double)BUF[q].z;                                   \
      ACC += h1.y * (double)BUF[q].w;                                   \
    } }
#define QLD(BUF, g, WP)                                                 \
  { _Pragma("unroll")                                                   \
    for (int q = 0; q < 4; ++q) BUF[q] = WP[(size_t)(4 * (g) + q) * 256]; }
#define QSTEP(BUF, g, WP, ACC)  QGRP(BUF, g, ACC) if ((g) + 2 < 4) QLD(BUF, (g) + 2, WP)

// ---- logits: consume group c from BUF, refill BUF with group c+3
#define LSTEP(BUF, c)                                                   \
  { _Pragma("unroll")                                                   \
    for (int i = 0; i < 8; ++i) {                                       \
      int t2 = ph * 128 + (c) * 8 + i;                                  \
      float2 qv = at.qv2[t2];                                           \
      la += (double)qv.y * (double)tanhf(qv.x + BUF[i]);                \
    }                                                                   \
    if ((c) + 3 < 16) {                                                 \
      _Pragma("unroll")                                                 \
      for (int i = 0; i < 8; ++i)                                       \
        BUF[i] = rT[(size_t)(((c) + 3) * 8 + i) * Sn];                  \
    } }

__global__ __launch_bounds__(1024, 4) void k_main(
    const float* __restrict__ inp,
    const double* __restrict__ wihe_e, const double* __restrict__ bias_e,
    const float* __restrict__ whh2_e,
    const double* __restrict__ wihe_d, const double* __restrict__ bias_d,
    const float* __restrict__ whh2_d,
    const float* __restrict__ wpref, const float* __restrict__ wpq,
    const float* __restrict__ v,
    float* __restrict__ refT,
    const uint32_t* __restrict__ keys,
    float* __restrict__ out) {
  __shared__ __align__(16) double sh_h[Hn];   // current h (f64)
  __shared__ double sh_g[Gn];                 // transformed gates
  __shared__ AttnS at;

  const int b   = blockIdx.x;
  const int tid = threadIdx.x;
  const int w   = tid >> 6;
  const int l   = tid & 63;
  const int gsel = tid >> 8;      // 0:i 1:f 2:g 3:o (wave-uniform)

  // per-thread gate-row constants (j = tid)
  const double bj_e = bias_e[tid], w0e = wihe_e[tid], w1e = wihe_e[Gn + tid];
  const double bj_d = bias_d[tid], w0d = wihe_d[tid], w1d = wihe_d[Gn + tid];
  const float vreg = (tid < Hn) ? v[tid] : 0.0f;

  double creg = 0.0;              // c for unit u = tid (threads 0..255)
  if (tid < Hn) sh_h[tid] = 0.0;
  __syncthreads();

  const float4* w4e = (const float4*)whh2_e + tid;   // stride 1024 float4/iter
  const float4* w4d = (const float4*)whh2_d + tid;
  const int part = tid >> 8, tcol = tid & 255;
  const float4* wr4 = (const float4*)wpref + (size_t)part * 16 * 256 + tcol;
  const float4* wq4 = (const float4*)wpq   + (size_t)part * 16 * 256 + tcol;

  // ================================================================ encoder
  // iteration s: phase A = gates_s(h_{s-1}) + refproj partials of h_{s-1};
  // phase B = h-update (waves 0-3) || refproj combine + refT[:,s-1] write
  // (waves 4-7). Extra iteration s==Sn handles refproj(h_511).
  for (int s = 0; s <= Sn; ++s) {
    if (s < Sn) {
      double x0 = (double)inp[((size_t)b * Sn + s) * 2 + 0];
      double x1 = (double)inp[((size_t)b * Sn + s) * 2 + 1];
      double acc = bj_e + x0 * w0e + x1 * w1e;
      float4 bA[4], bB[4];
      GLD(bA, 0, w4e)
      GLD(bB, 1, w4e)
      GSTEP(bA, 0, w4e)  GSTEP(bB, 1, w4e)  GSTEP(bA, 2, w4e)  GSTEP(bB, 3, w4e)
      GSTEP(bA, 4, w4e)  GSTEP(bB, 5, w4e)  GSTEP(bA, 6, w4e)  GSTEP(bB, 7, w4e)
      GSTEP(bA, 8, w4e)  GSTEP(bB, 9, w4e)  GSTEP(bA, 10, w4e) GSTEP(bB, 11, w4e)
      GSTEP(bA, 12, w4e) GSTEP(bB, 13, w4e) GSTEP(bA, 14, w4e) GSTEP(bB, 15, w4e)
      sh_g[tid] = (gsel == 2) ? tanh(acc) : sigmoid64(acc);
    }
    if (s > 0) {
      // refproj of h_{s-1} (currently in sh_h): exact split-k pattern
      double racc = 0.0;
      float4 qA[4], qB[4];
      QLD(qA, 0, wr4)
      QLD(qB, 1, wr4)
      QSTEP(qA, 0, wr4, racc) QSTEP(qB, 1, wr4, racc)
      QSTEP(qA, 2, wr4, racc) QSTEP(qB, 3, wr4, racc)
      at.qpart[part][tcol] = racc;
    }
    __syncthreads();                       // S1
    if (s < Sn && tid < Hn) {
      double ti = sh_g[tid];
      double tf = sh_g[256 + tid];
      double tg = sh_g[512 + tid];
      double to = sh_g[768 + tid];
      double cn = tf * creg + ti * tg;     // == sig(gf)*c + sig(gi)*tanh(gg)
      double hn = to * tanh(cn);
      creg = cn;
      sh_h[tid] = hn;
    }
    if (s > 0 && tid >= 256 && tid < 512) {
      int u = tid - 256;
      double r = (at.qpart[0][u] + at.qpart[1][u]) +
                 (at.qpart[2][u] + at.qpart[3][u]);
      refT[((size_t)b * Hn + u) * Sn + (s - 1)] = (float)r;
    }
    __syncthreads();                       // S2
  }

  // ================================================================ decoder
  const int sE = tid & 511, ph = tid >> 9;
  const float* rT = refT + ((size_t)b * Hn + ph * 128) * Sn + sE;   // constant
  int ch = 0;                               // START; uniform across threads
  unsigned mbits = (l == 0) ? 1u : 0u;      // bit k: s = l + 64k masked
  for (int t = 0; t < NSTEP; ++t) {
    const int par = t & 1;
    // A: cell (exact k-ascending order; ping-pong prefetched weights)
    {
      int col = __builtin_amdgcn_readfirstlane(ch);
      double x0 = (double)inp[((size_t)b * Sn + col) * 2 + 0];
      double x1 = (double)inp[((size_t)b * Sn + col) * 2 + 1];
      double acc = bj_d + x0 * w0d + x1 * w1d;
      float4 bA[4], bB[4];
      GLD(bA, 0, w4d)
      GLD(bB, 1, w4d)
      GSTEP(bA, 0, w4d)  GSTEP(bB, 1, w4d)  GSTEP(bA, 2, w4d)  GSTEP(bB, 3, w4d)
      GSTEP(bA, 4, w4d)  GSTEP(bB, 5, w4d)  GSTEP(bA, 6, w4d)  GSTEP(bB, 7, w4d)
      GSTEP(bA, 8, w4d)  GSTEP(bB, 9, w4d)  GSTEP(bA, 10, w4d) GSTEP(bB, 11, w4d)
      GSTEP(bA, 12, w4d) GSTEP(bB, 13, w4d) GSTEP(bA, 14, w4d) GSTEP(bB, 15, w4d)
      sh_g[tid] = (gsel == 2) ? tanh(acc) : sigmoid64(acc);
    }
    __syncthreads();                       // S1
    // B: h-update (waves 0-3) || gumbel precompute (waves 8-15, else idle).
    // sg double-buffer isolates this write from step t-1's reads.
    if (tid < Hn) {
      double ti = sh_g[tid];
      double tf = sh_g[256 + tid];
      double tg = sh_g[512 + tid];
      double to = sh_g[768 + tid];
      double cn = tf * creg + ti * tg;
      double hn = to * tanh(cn);
      creg = cn;
      sh_h[tid] = hn;
    } else if (tid >= 512) {
      const uint32_t k0 = keys[2 * t], k1 = keys[2 * t + 1];
      int s0 = tid - 512;
      uint32_t wrd = random_word(k0, k1, (uint32_t)(b * Sn + s0));
      float uf = __uint_as_float((wrd >> 9) | 0x3f800000u) - 1.0f;
      uf = fmaxf(uf, 1.17549435e-38f);
      at.sg[par][s0] = -log(-log((double)uf));
    }
    __syncthreads();                       // S2
    // early-issue refT group 0 (hides under qproj; refT is read-only here)
    float sA[8], sB[8], sC[8];
    #pragma unroll
    for (int i = 0; i < 8; ++i) sA[i] = rT[(size_t)i * Sn];
    // C: q-projection (exact split-k pattern; ping-pong prefetch)
    {
      double qa = 0.0;
      float4 qA[4], qB[4];
      QLD(qA, 0, wq4)
      QLD(qB, 1, wq4)
      QSTEP(qA, 0, wq4, qa) QSTEP(qB, 1, wq4, qa)
      QSTEP(qA, 2, wq4, qa) QSTEP(qB, 3, wq4, qa)
      at.qpart[part][tcol] = qa;
    }
    __syncthreads();                       // S3
    // early-issue refT group 1 (hides under combine)
    #pragma unroll
    for (int i = 0; i < 8; ++i) sB[i] = rT[(size_t)(8 + i) * Sn];
    if (tid < Hn) {
      double q = (at.qpart[0][tid] + at.qpart[1][tid]) +
                 (at.qpart[2][tid] + at.qpart[3][tid]);
      at.qv2[tid] = make_float2((float)q, vreg);
    }
    __syncthreads();                       // S4
    // early-issue refT group 2
    #pragma unroll
    for (int i = 0; i < 8; ++i) sC[i] = rT[(size_t)(16 + i) * Sn];
    // E: logits (tanhf, f64 acc, t-ascending) -- 3-deep static pipeline
    {
      double la = 0.0;
      LSTEP(sA, 0)  LSTEP(sB, 1)  LSTEP(sC, 2)
      LSTEP(sA, 3)  LSTEP(sB, 4)  LSTEP(sC, 5)
      LSTEP(sA, 6)  LSTEP(sB, 7)  LSTEP(sC, 8)
      LSTEP(sA, 9)  LSTEP(sB, 10) LSTEP(sC, 11)
      LSTEP(sA, 12) LSTEP(sB, 13) LSTEP(sC, 14)
      LSTEP(sA, 15)
      at.p2[ph][sE] = la;
    }
    __syncthreads();                       // S5
    // F: inline sampling (register masks), bit-identical compare sequence
    double slv[8];
    {
      #pragma unroll
      for (int k = 0; k < 8; ++k) {
        int s2 = l + k * 64;
        slv[k] = (mbits >> k) & 1u ? (double)MASK_VAL
                                   : (at.p2[0][s2] + at.p2[1][s2]);
      }
      double bz = slv[0] + at.sg[par][l];
      int bi = l;
      #pragma unroll
      for (int k = 1; k < 8; ++k) {
        int s2 = l + k * 64;
        double z2 = slv[k] + at.sg[par][s2];
        if (z2 > bz || (z2 == bz && s2 < bi)) { bz = z2; bi = s2; }
      }
      #pragma unroll
      for (int m = 32; m >= 1; m >>= 1) {
        double oz = __shfl_xor(bz, m);
        int    oi = __shfl_xor(bi, m);
        if (oz > bz || (oz == bz && oi < bi)) { bz = oz; bi = oi; }
      }
      ch = bi;
    }
    // logsumexp (wave 1 only) + output writes
    if (w == 1) {
      double bm = slv[0];
      #pragma unroll
      for (int k = 1; k < 8; ++k) bm = fmax(bm, slv[k]);
      #pragma unroll
      for (int m = 32; m >= 1; m >>= 1) bm = fmax(bm, __shfl_xor(bm, m));
      double ps = 0.0;
      #pragma unroll
      for (int k = 0; k < 8; ++k) ps += exp(slv[k] - bm);
      #pragma unroll
      for (int m = 32; m >= 1; m >>= 1) ps += __shfl_xor(ps, m);
      if (l == 0) {
        double lse = bm + log(ps);
        double slch = at.p2[0][ch] + at.p2[1][ch];   // ch is never masked
        double lp = slch - lse;
        out[(size_t)b * NSTEP + t] = (float)lp;
        out[(size_t)Bn * NSTEP + (size_t)b * Sn + (t + 1)] = (float)ch;
      }
    }
    // register mask update (every thread, every wave)
    if ((ch & 63) == l) mbits |= 1u << (ch >> 6);
    // no trailing barrier: next step's S1..S5 separate p2/sg/qv2 hazards;
    // sg double-buffer isolates the next gumbel write from this step's reads
  }
}

// ---------------------------------------------------------------- launch
extern "C" void kernel_launch(void* const* d_in, const int* in_sizes, int n_in,
                              void* d_out, int out_size, void* d_ws, size_t ws_size,
                              hipStream_t stream) {
  const float* inp  = (const float*)d_in[0];
  const float* wemb = (const float*)d_in[1];
  const float* eWih = (const float*)d_in[2];
  const float* eWhh = (const float*)d_in[3];
  const float* ebih = (const float*)d_in[4];
  const float* ebhh = (const float*)d_in[5];
  const float* dWih = (const float*)d_in[6];
  const float* dWhh = (const float*)d_in[7];
  const float* dbih = (const float*)d_in[8];
  const float* dbhh = (const float*)d_in[9];
  const float* Wq   = (const float*)d_in[10];
  const float* Wref = (const float*)d_in[11];
  const float* v    = (const float*)d_in[12];
  float* out = (float*)d_out;

  char* ws = (char*)d_ws;
  size_t off = 0;
  auto alloc = [&](size_t bytes) -> void* {
    void* p = (void*)(ws + off);
    off += (bytes + 255) & ~(size_t)255;
    return p;
  };
  // total ~137 MB (proven workspace level)
  float*    refT   = (float*)   alloc((size_t)Bn * Sn * Hn * sizeof(float));   // 134 MB
  float*    whh2_e = (float*)   alloc((size_t)Hn * Gn * sizeof(float));        // 1 MB packed
  float*    whh2_d = (float*)   alloc((size_t)Hn * Gn * sizeof(float));        // 1 MB packed
  float*    wpq    = (float*)   alloc((size_t)Hn * Hn * sizeof(float));
  float*    wpref  = (float*)   alloc((size_t)Hn * Hn * sizeof(float));
  double*   wihe_e = (double*)  alloc(2 * Gn * sizeof(double));
  double*   wihe_d = (double*)  alloc(2 * Gn * sizeof(double));
  double*   bias_e = (double*)  alloc(Gn * sizeof(double));
  double*   bias_d = (double*)  alloc(Gn * sizeof(double));
  uint32_t* keys   = (uint32_t*)alloc(2 * NSTEP * sizeof(uint32_t));
  (void)ws_size; (void)in_sizes; (void)n_in; (void)out_size;

  k_wihe<<<Gn / 256, 256, 0, stream>>>(wemb, eWih, ebih, ebhh, wihe_e, bias_e);
  k_wihe<<<Gn / 256, 256, 0, stream>>>(wemb, dWih, dbih, dbhh, wihe_d, bias_d);
  k_keys<<<2, 256, 0, stream>>>(keys);
  k_pack_whh<<<(Hn * Gn) / 256, 256, 0, stream>>>(eWhh, whh2_e);
  k_pack_whh<<<(Hn * Gn) / 256, 256, 0, stream>>>(dWhh, whh2_d);
  k_pack_w256<<<(Hn * Hn) / 256, 256, 0, stream>>>(Wq, wpq);
  k_pack_w256<<<(Hn * Hn) / 256, 256, 0, stream>>>(Wref, wpref);
  k_init<<<1, 256, 0, stream>>>(out);

  k_main<<<Bn, 1024, 0, stream>>>(
      inp, wihe_e, bias_e, whh2_e, wihe_d, bias_d, whh2_d,
      wpref, wpq, v, refT, keys, out);
}

// Round 5
// 27258.682 us; speedup vs baseline: 9.2274x; 9.2274x over previous
//
#include <hip/hip_runtime.h>
#include <stdint.h>
#include <math.h>

// Problem dims
#define Bn 256
#define Sn 512
#define En 256
#define Hn 256
#define Gn 1024            // 4*H
#define NSTEP 511          // S-1 decoder steps
#define MASK_VAL -100000.0

// Verified rounds 1-3,7-11: partitionable threefry + f64 compute -> absmax=0.
#define PARTITIONABLE 1

// ---------------------------------------------------------------- threefry
__device__ __forceinline__ uint32_t rotl32(uint32_t v, int d) {
  return (v << d) | (v >> (32 - d));
}

__device__ __forceinline__ void threefry2x32(uint32_t k0, uint32_t k1,
                                             uint32_t x0, uint32_t x1,
                                             uint32_t& o0, uint32_t& o1) {
  const uint32_t ks2 = k0 ^ k1 ^ 0x1BD11BDAu;
  x0 += k0; x1 += k1;
  x0 += x1; x1 = rotl32(x1, 13); x1 ^= x0;
  x0 += x1; x1 = rotl32(x1, 15); x1 ^= x0;
  x0 += x1; x1 = rotl32(x1, 26); x1 ^= x0;
  x0 += x1; x1 = rotl32(x1,  6); x1 ^= x0;
  x0 += k1; x1 += ks2 + 1u;
  x0 += x1; x1 = rotl32(x1, 17); x1 ^= x0;
  x0 += x1; x1 = rotl32(x1, 29); x1 ^= x0;
  x0 += x1; x1 = rotl32(x1, 16); x1 ^= x0;
  x0 += x1; x1 = rotl32(x1, 24); x1 ^= x0;
  x0 += ks2; x1 += k0 + 2u;
  x0 += x1; x1 = rotl32(x1, 13); x1 ^= x0;
  x0 += x1; x1 = rotl32(x1, 15); x1 ^= x0;
  x0 += x1; x1 = rotl32(x1, 26); x1 ^= x0;
  x0 += x1; x1 = rotl32(x1,  6); x1 ^= x0;
  x0 += k0; x1 += k1 + 3u;
  x0 += x1; x1 = rotl32(x1, 17); x1 ^= x0;
  x0 += x1; x1 = rotl32(x1, 29); x1 ^= x0;
  x0 += x1; x1 = rotl32(x1, 16); x1 ^= x0;
  x0 += x1; x1 = rotl32(x1, 24); x1 ^= x0;
  x0 += k1; x1 += ks2 + 4u;
  x0 += x1; x1 = rotl32(x1, 13); x1 ^= x0;
  x0 += x1; x1 = rotl32(x1, 15); x1 ^= x0;
  x0 += x1; x1 = rotl32(x1, 26); x1 ^= x0;
  x0 += x1; x1 = rotl32(x1,  6); x1 ^= x0;
  x0 += ks2; x1 += k0 + 5u;
  o0 = x0; o1 = x1;
}

__device__ __forceinline__ uint32_t random_word(uint32_t k0, uint32_t k1, uint32_t n) {
#if PARTITIONABLE
  uint32_t o0, o1;
  threefry2x32(k0, k1, 0u, n, o0, o1);
  return o0 ^ o1;
#else
  const uint32_t half = (Bn * Sn) / 2;
  uint32_t lane = (n < half) ? n : (n - half);
  uint32_t o0, o1;
  threefry2x32(k0, k1, lane, lane + half, o0, o1);
  return (n < half) ? o0 : o1;
#endif
}

__device__ __forceinline__ double sigmoid64(double x) {
  return 1.0 / (1.0 + exp(-x));
}

// ---------------------------------------------------------------- prep
__global__ __launch_bounds__(256) void k_wihe(const float* __restrict__ wemb,
                                              const float* __restrict__ wih,
                                              const float* __restrict__ bih,
                                              const float* __restrict__ bhh,
                                              double* __restrict__ wihe,
                                              double* __restrict__ bias) {
  int j = blockIdx.x * blockDim.x + threadIdx.x;
  if (j >= Gn) return;
  double a0 = 0.0, a1 = 0.0;
  for (int e = 0; e < En; ++e) {
    double w = (double)wih[j * En + e];
    a0 += (double)wemb[e] * w;
    a1 += (double)wemb[En + e] * w;
  }
  wihe[j] = a0;
  wihe[Gn + j] = a1;
  bias[j] = (double)bih[j] + (double)bhh[j];
}

__global__ __launch_bounds__(256) void k_keys(uint32_t* __restrict__ keys) {
  int j = blockIdx.x * blockDim.x + threadIdx.x;
  if (j >= NSTEP) return;
#if PARTITIONABLE
  uint32_t o0, o1;
  threefry2x32(0u, 1u, 0u, (uint32_t)j, o0, o1);
  keys[2 * j] = o0; keys[2 * j + 1] = o1;
#else
  uint32_t w[2];
  #pragma unroll
  for (int q = 0; q < 2; ++q) {
    uint32_t m = (uint32_t)(2 * j + q);
    uint32_t lane = (m < NSTEP) ? m : (m - NSTEP);
    uint32_t o0, o1;
    threefry2x32(0u, 1u, lane, lane + NSTEP, o0, o1);
    w[q] = (m < NSTEP) ? o0 : o1;
  }
  keys[2 * j] = w[0]; keys[2 * j + 1] = w[1];
#endif
}

// dst[k][j] = src[j][k]  (256x256 f32 transpose: Wq, Wref)
__global__ __launch_bounds__(256) void k_t32(const float* __restrict__ src,
                                             float* __restrict__ dst) {
  int idx = blockIdx.x * blockDim.x + threadIdx.x;
  int k = idx >> 8, j = idx & 255;
  dst[idx] = src[j * Hn + k];
}

// dst[k][j] = src[j][k]  (Whh: 1024 rows j, 256 cols k -> 256 x 1024)
__global__ __launch_bounds__(256) void k_t32w(const float* __restrict__ src,
                                              float* __restrict__ dst) {
  int idx = blockIdx.x * blockDim.x + threadIdx.x;   // 256*1024 elems
  int k = idx >> 10, j = idx & 1023;
  dst[idx] = src[j * Hn + k];
}

__global__ __launch_bounds__(256) void k_init(float* __restrict__ out) {
  int idx = blockIdx.x * blockDim.x + threadIdx.x;
  if (idx < Bn) out[Bn * NSTEP + idx * Sn] = 0.0f;   // indices[:,0] = START
}

// ---------------------------------------------------------------- main
// Block b owns batch row b end-to-end (zero cross-block communication).
// r16 = EXACT r12 (27.8 ms, absmax 0, zero spill) + two individually-safe
// deltas (both ran spill-free inside r14):
//  A. gumbel moved from phase A (serial, waves 0-7) to phase B where waves
//     8-15 are idle during the h-update. Same (b,s,key) -> same values.
//  B. qf+vbuf fused into one float2 LDS read in the logits hot loop
//     (128 ds_read_b64 instead of 256 ds_read_b32 per thread-step).
// r13/r15 lesson (2x burned): any register staging whose live range spans
// phases/barriers or uses deep macro pipelines gets demoted to SCRATCH by
// this compiler (WRITE_SIZE 1e6 -> 2e8 KB signature). Only r12's st[8]
// declared-and-consumed-inside-one-loop-body pattern is proven safe.
struct AttnS {
  double qpart[4][256];   // 8 KB
  double p2[2][512];      // 8 KB
  double sg[2][512];      // 8 KB  gumbel, double-buffered by t&1
  float2 qv2[256];        // 2 KB  {qf, v} fused
};

__global__ __launch_bounds__(1024, 4) void k_main(
    const float* __restrict__ inp,
    const double* __restrict__ wihe_e, const double* __restrict__ bias_e,
    const float* __restrict__ whhT_e,
    const double* __restrict__ wihe_d, const double* __restrict__ bias_d,
    const float* __restrict__ whhT_d,
    const float* __restrict__ wrefT, const float* __restrict__ wqT,
    const float* __restrict__ v,
    float* __restrict__ refT,
    const uint32_t* __restrict__ keys,
    float* __restrict__ out) {
  __shared__ __align__(16) double sh_h[Hn];   // current h (f64)
  __shared__ double sh_g[Gn];                 // transformed gates
  __shared__ AttnS at;

  const int b   = blockIdx.x;
  const int tid = threadIdx.x;
  const int w   = tid >> 6;
  const int l   = tid & 63;
  const int gsel = tid >> 8;      // 0:i 1:f 2:g 3:o (wave-uniform)

  // per-thread gate-row constants (j = tid)
  const double bj_e = bias_e[tid], w0e = wihe_e[tid], w1e = wihe_e[Gn + tid];
  const double bj_d = bias_d[tid], w0d = wihe_d[tid], w1d = wihe_d[Gn + tid];
  const float vreg = (tid < Hn) ? v[tid] : 0.0f;

  double creg = 0.0;              // c for unit u = tid (threads 0..255)
  if (tid < Hn) sh_h[tid] = 0.0;
  __syncthreads();

  const float* wcol_e = whhT_e + tid;
  const float* wcol_d = whhT_d + tid;
  const int part = tid >> 8, tcol = tid & 255;

  // ================================================================ encoder
  for (int s = 0; s < Sn; ++s) {
    // cell gates: exact k-ascending order (double2 reads, same math);
    // transform applied by the OWNING thread (same input -> same value)
    {
      double x0 = (double)inp[((size_t)b * Sn + s) * 2 + 0];
      double x1 = (double)inp[((size_t)b * Sn + s) * 2 + 1];
      double acc = bj_e + x0 * w0e + x1 * w1e;
      #pragma unroll 4
      for (int k = 0; k < Hn; k += 2) {
        double2 hv = *(const double2*)&sh_h[k];
        acc += hv.x * (double)wcol_e[(size_t)k << 10];
        acc += hv.y * (double)wcol_e[(size_t)(k + 1) << 10];
      }
      sh_g[tid] = (gsel == 2) ? tanh(acc) : sigmoid64(acc);
    }
    __syncthreads();                       // S1
    if (tid < Hn) {
      double ti = sh_g[tid];
      double tf = sh_g[256 + tid];
      double tg = sh_g[512 + tid];
      double to = sh_g[768 + tid];
      double cn = tf * creg + ti * tg;     // == sig(gf)*c + sig(gi)*tanh(gg)
      double hn = to * tanh(cn);
      creg = cn;
      sh_h[tid] = hn;
    }
    __syncthreads();                       // S2
    // refproj column s (verified split-k pattern, f64 h)
    {
      double racc = 0.0;
      #pragma unroll 8
      for (int i = 0; i < 64; ++i) {
        int k = part * 64 + i;
        racc += sh_h[k] * (double)wrefT[(size_t)k * Hn + tcol];
      }
      at.qpart[part][tcol] = racc;
    }
    __syncthreads();                       // S3
    if (tid < Hn) {
      double r = (at.qpart[0][tid] + at.qpart[1][tid]) +
                 (at.qpart[2][tid] + at.qpart[3][tid]);
      refT[((size_t)b * Hn + tid) * Sn + s] = (float)r;
    }
  }

  // ================================================================ decoder
  int ch = 0;                               // START; uniform across threads
  unsigned mbits = (l == 0) ? 1u : 0u;      // bit k: s = l + 64k masked
  for (int t = 0; t < NSTEP; ++t) {
    const int par = t & 1;
    // A: cell (exact k-ascending order; double2 reads; uniform column scalar)
    {
      int col = __builtin_amdgcn_readfirstlane(ch);
      double x0 = (double)inp[((size_t)b * Sn + col) * 2 + 0];
      double x1 = (double)inp[((size_t)b * Sn + col) * 2 + 1];
      double acc = bj_d + x0 * w0d + x1 * w1d;
      #pragma unroll 4
      for (int k = 0; k < Hn; k += 2) {
        double2 hv = *(const double2*)&sh_h[k];
        acc += hv.x * (double)wcol_d[(size_t)k << 10];
        acc += hv.y * (double)wcol_d[(size_t)(k + 1) << 10];
      }
      sh_g[tid] = (gsel == 2) ? tanh(acc) : sigmoid64(acc);
    }
    __syncthreads();                       // S1
    // B: h-update (waves 0-3) || gumbel precompute (waves 8-15, else idle).
    // sg double-buffer isolates this write from step t-1's sampling reads
    // (sampling t-1 reads sg[par^1]; S1 separates it from this phase anyway).
    if (tid < Hn) {
      double ti = sh_g[tid];
      double tf = sh_g[256 + tid];
      double tg = sh_g[512 + tid];
      double to = sh_g[768 + tid];
      double cn = tf * creg + ti * tg;
      double hn = to * tanh(cn);
      creg = cn;
      sh_h[tid] = hn;
    } else if (tid >= 512) {
      const uint32_t k0 = keys[2 * t], k1 = keys[2 * t + 1];
      int s0 = tid - 512;
      uint32_t wrd = random_word(k0, k1, (uint32_t)(b * Sn + s0));
      float uf = __uint_as_float((wrd >> 9) | 0x3f800000u) - 1.0f;
      uf = fmaxf(uf, 1.17549435e-38f);
      at.sg[par][s0] = -log(-log((double)uf));
    }
    __syncthreads();                       // S2
    // C: q-projection (r12 pattern)
    {
      double qa = 0.0;
      #pragma unroll 8
      for (int i = 0; i < 64; ++i) {
        int k = part * 64 + i;
        qa += sh_h[k] * (double)wqT[(size_t)k * Hn + tcol];
      }
      at.qpart[part][tcol] = qa;
    }
    __syncthreads();                       // S3
    if (tid < Hn) {
      double q = (at.qpart[0][tid] + at.qpart[1][tid]) +
                 (at.qpart[2][tid] + at.qpart[3][tid]);
      at.qv2[tid] = make_float2((float)q, vreg);
    }
    __syncthreads();                       // S4
    // E: logits: r12 exact (tanhf, f64 acc, t-ascending, 8-deep staging
    // declared INSIDE the c loop -- the only staging pattern this compiler
    // keeps in registers). qf+v as one float2 read (delta B).
    {
      const int sE = tid & 511, ph = tid >> 9;
      const float* rT = refT + ((size_t)b * Hn + ph * 128) * Sn + sE;
      double la = 0.0;
      for (int c = 0; c < 16; ++c) {
        float st[8];
        #pragma unroll
        for (int i = 0; i < 8; ++i)
          st[i] = rT[(size_t)(c * 8 + i) * Sn];
        #pragma unroll
        for (int i = 0; i < 8; ++i) {
          int t2 = ph * 128 + c * 8 + i;
          float2 qv = at.qv2[t2];          // .x = qf[t2], .y = v[t2]
          la += (double)qv.y * (double)tanhf(qv.x + st[i]);
        }
      }
      at.p2[ph][sE] = la;
    }
    __syncthreads();                       // S5
    // F: inline sampling (register masks), bit-identical compare sequence
    double slv[8];
    {
      #pragma unroll
      for (int k = 0; k < 8; ++k) {
        int s2 = l + k * 64;
        slv[k] = (mbits >> k) & 1u ? (double)MASK_VAL
                                   : (at.p2[0][s2] + at.p2[1][s2]);
      }
      double bz = slv[0] + at.sg[par][l];
      int bi = l;
      #pragma unroll
      for (int k = 1; k < 8; ++k) {
        int s2 = l + k * 64;
        double z2 = slv[k] + at.sg[par][s2];
        if (z2 > bz || (z2 == bz && s2 < bi)) { bz = z2; bi = s2; }
      }
      #pragma unroll
      for (int m = 32; m >= 1; m >>= 1) {
        double oz = __shfl_xor(bz, m);
        int    oi = __shfl_xor(bi, m);
        if (oz > bz || (oz == bz && oi < bi)) { bz = oz; bi = oi; }
      }
      ch = bi;
    }
    // logsumexp (wave 1 only) + output writes
    if (w == 1) {
      double bm = slv[0];
      #pragma unroll
      for (int k = 1; k < 8; ++k) bm = fmax(bm, slv[k]);
      #pragma unroll
      for (int m = 32; m >= 1; m >>= 1) bm = fmax(bm, __shfl_xor(bm, m));
      double ps = 0.0;
      #pragma unroll
      for (int k = 0; k < 8; ++k) ps += exp(slv[k] - bm);
      #pragma unroll
      for (int m = 32; m >= 1; m >>= 1) ps += __shfl_xor(ps, m);
      if (l == 0) {
        double lse = bm + log(ps);
        double slch = at.p2[0][ch] + at.p2[1][ch];   // ch is never masked
        double lp = slch - lse;
        out[(size_t)b * NSTEP + t] = (float)lp;
        out[(size_t)Bn * NSTEP + (size_t)b * Sn + (t + 1)] = (float)ch;
      }
    }
    // register mask update (every thread, every wave)
    if ((ch & 63) == l) mbits |= 1u << (ch >> 6);
    // no trailing barrier: next step's S1..S5 separate p2/sg/qv2 hazards;
    // sg double-buffer isolates the next gumbel write from this step's reads
  }
}

// ---------------------------------------------------------------- launch
extern "C" void kernel_launch(void* const* d_in, const int* in_sizes, int n_in,
                              void* d_out, int out_size, void* d_ws, size_t ws_size,
                              hipStream_t stream) {
  const float* inp  = (const float*)d_in[0];
  const float* wemb = (const float*)d_in[1];
  const float* eWih = (const float*)d_in[2];
  const float* eWhh = (const float*)d_in[3];
  const float* ebih = (const float*)d_in[4];
  const float* ebhh = (const float*)d_in[5];
  const float* dWih = (const float*)d_in[6];
  const float* dWhh = (const float*)d_in[7];
  const float* dbih = (const float*)d_in[8];
  const float* dbhh = (const float*)d_in[9];
  const float* Wq   = (const float*)d_in[10];
  const float* Wref = (const float*)d_in[11];
  const float* v    = (const float*)d_in[12];
  float* out = (float*)d_out;

  char* ws = (char*)d_ws;
  size_t off = 0;
  auto alloc = [&](size_t bytes) -> void* {
    void* p = (void*)(ws + off);
    off += (bytes + 255) & ~(size_t)255;
    return p;
  };
  // total ~137 MB (proven workspace level)
  float*    refT   = (float*)   alloc((size_t)Bn * Sn * Hn * sizeof(float));   // 134 MB
  float*    whhT_e = (float*)   alloc((size_t)Hn * Gn * sizeof(float));        // 1 MB
  float*    whhT_d = (float*)   alloc((size_t)Hn * Gn * sizeof(float));        // 1 MB
  float*    wqT    = (float*)   alloc((size_t)Hn * Hn * sizeof(float));
  float*    wrefT  = (float*)   alloc((size_t)Hn * Hn * sizeof(float));
  double*   wihe_e = (double*)  alloc(2 * Gn * sizeof(double));
  double*   wihe_d = (double*)  alloc(2 * Gn * sizeof(double));
  double*   bias_e = (double*)  alloc(Gn * sizeof(double));
  double*   bias_d = (double*)  alloc(Gn * sizeof(double));
  uint32_t* keys   = (uint32_t*)alloc(2 * NSTEP * sizeof(uint32_t));
  (void)ws_size; (void)in_sizes; (void)n_in; (void)out_size;

  k_wihe<<<Gn / 256, 256, 0, stream>>>(wemb, eWih, ebih, ebhh, wihe_e, bias_e);
  k_wihe<<<Gn / 256, 256, 0, stream>>>(wemb, dWih, dbih, dbhh, wihe_d, bias_d);
  k_keys<<<2, 256, 0, stream>>>(keys);
  k_t32<<<(Hn * Hn) / 256, 256, 0, stream>>>(Wq, wqT);
  k_t32<<<(Hn * Hn) / 256, 256, 0, stream>>>(Wref, wrefT);
  k_t32w<<<(Hn * Gn) / 256, 256, 0, stream>>>(eWhh, whhT_e);
  k_t32w<<<(Hn * Gn) / 256, 256, 0, stream>>>(dWhh, whhT_d);
  k_init<<<1, 256, 0, stream>>>(out);

  k_main<<<Bn, 1024, 0, stream>>>(
      inp, wihe_e, bias_e, whhT_e, wihe_d, bias_d, whhT_d,
      wrefT, wqT, v, refT, keys, out);
}